// Round 10
// baseline (820.493 us; speedup 1.0000x reference)
//
#include <hip/hip_runtime.h>
#include <stdint.h>

typedef unsigned short u16;
typedef unsigned int u32;
typedef unsigned char u8;
typedef __bf16 bf16x8 __attribute__((ext_vector_type(8)));
typedef float f32x4 __attribute__((ext_vector_type(4)));

#define NGRAPH 128

__device__ __forceinline__ float b2f(u16 u) {
    union { u32 i; float f; } c; c.i = ((u32)u) << 16; return c.f;
}
__device__ __forceinline__ u16 f2b(float f) {
    union { float f; u32 i; } c; c.f = f;
    u32 r = c.i + 0x7fffu + ((c.i >> 16) & 1u);
    return (u16)(r >> 16);
}

// ---- sentinel (error paths only) ----
__global__ void k_sentinel(u16* __restrict__ out, int n, u16 pat) {
    int i = blockIdx.x * 256 + threadIdx.x;
    if (i < n) out[i] = pat;
}

// ---- fused init: zero deg/pool, dtype detect (block 0), root search (block 1) ----
__global__ __launch_bounds__(256) void k_init(const u16* __restrict__ x, const int* __restrict__ batch,
                                              int* __restrict__ deg, float* __restrict__ pool,
                                              int* __restrict__ flag, int* __restrict__ root,
                                              int N, int B) {
    __shared__ int cnt;
    int i = blockIdx.x * 256 + threadIdx.x;
    if (i < N + 1) deg[i] = 0;
    if (i < B * 256) pool[i] = 0.0f;
    if (blockIdx.x == 0) {
        if (threadIdx.x == 0) cnt = 0;
        __syncthreads();
        int weird = 0;
        for (int k = threadIdx.x; k < 4096; k += 256) {
            u16 u = x[2 * k];                  // fp32 inputs: random low-mantissa halves
            int e = (u >> 7) & 0xff;
            if (e != 0 && (e < 100 || e > 140)) weird++;
        }
        atomicAdd(&cnt, weird);
        __syncthreads();
        if (threadIdx.x == 0) *flag = (cnt > 1024) ? 1 : 0;   // 1 = fp32 inputs
    } else if (blockIdx.x == 1) {
        int b = threadIdx.x;
        if (b <= B) {
            int lo = 0, hi = N;
            while (lo < hi) { int mid = (lo + hi) >> 1; if (batch[mid] < b) lo = mid + 1; else hi = mid; }
            root[b] = lo;
        }
    }
}

// ---- vectorized convert ----
__global__ __launch_bounds__(256) void k_cvt4(const void* __restrict__ src, u16* __restrict__ dst,
                                              int n4, const int* __restrict__ flag) {
    int i = blockIdx.x * 256 + threadIdx.x;
    if (i >= n4) return;
    if (*flag) {
        float4 v = ((const float4*)src)[i];
        ushort4 o;
        o.x = f2b(v.x); o.y = f2b(v.y); o.z = f2b(v.z); o.w = f2b(v.w);
        ((ushort4*)dst)[i] = o;
    } else {
        ((ushort4*)dst)[i] = ((const ushort4*)src)[i];
    }
}

// ---- small-vector convert: 18 blocks x 256 ----
__global__ __launch_bounds__(256) void k_cvt_small(
    const void* p0, const void* p1, const void* p2, const void* p3, const void* p4,
    const void* p5, const void* p6, const void* p7, const void* p8, const void* p9,
    const void* p10, const void* p11, const void* p12, const void* p13, const void* p14,
    const void* p15, const void* p16, const void* p17,
    u16* __restrict__ dst, const int* __restrict__ flag) {
    const void* ps[18] = {p0,p1,p2,p3,p4,p5,p6,p7,p8,p9,p10,p11,p12,p13,p14,p15,p16,p17};
    int f = *flag;
    int vec = blockIdx.x;
    int j = threadIdx.x;
    const void* s = ps[vec];
    dst[vec * 256 + j] = f ? f2b(((const float*)s)[j]) : ((const u16*)s)[j];
}

// ---- dual transpose 256x256 ----
__global__ __launch_bounds__(256) void k_tr2(const u16* __restrict__ w1, u16* __restrict__ wt1,
                                             const u16* __restrict__ w2, u16* __restrict__ wt2) {
    int idx = blockIdx.x * 256 + threadIdx.x;
    int halfsel = idx >> 16;
    int j = idx & 65535;
    int n = j >> 8, k = j & 255;
    if (halfsel == 0) wt1[n * 256 + k] = w1[k * 256 + n];
    else              wt2[n * 256 + k] = w2[k * 256 + n];
}

__global__ __launch_bounds__(256) void k_hist(const int* __restrict__ ei, int* __restrict__ deg, int E) {
    int e = blockIdx.x * 256 + threadIdx.x;
    if (e < E) atomicAdd(&deg[ei[E + e]], 1);
}

__global__ __launch_bounds__(256) void k_scan1(const int* __restrict__ in, int* __restrict__ out,
                                               int* __restrict__ bsums, int total) {
    __shared__ int lds[256];
    int tid = threadIdx.x;
    int base = blockIdx.x * 2048 + tid * 8;
    int v[8]; int ts = 0;
#pragma unroll
    for (int r = 0; r < 8; r++) { int i = base + r; int x = (i < total) ? in[i] : 0; v[r] = x; ts += x; }
    lds[tid] = ts;
    __syncthreads();
    for (int off = 1; off < 256; off <<= 1) {
        int t = (tid >= off) ? lds[tid - off] : 0;
        __syncthreads();
        lds[tid] += t;
        __syncthreads();
    }
    int run = lds[tid] - ts;
#pragma unroll
    for (int r = 0; r < 8; r++) { int i = base + r; if (i < total) out[i] = run; run += v[r]; }
    if (tid == 255) bsums[blockIdx.x] = lds[255];
}

__global__ void k_scan2(int* __restrict__ bsums, int nb) {
    if (threadIdx.x == 0 && blockIdx.x == 0) {
        int run = 0;
        for (int i = 0; i < nb; i++) { int t = bsums[i]; bsums[i] = run; run += t; }
    }
}

__global__ __launch_bounds__(256) void k_scan3(const int* __restrict__ pscan, const int* __restrict__ bsums,
                                               int* __restrict__ ptr, int* __restrict__ cursor,
                                               int total, int N) {
    int i = blockIdx.x * 256 + threadIdx.x;
    if (i >= total) return;
    int val = pscan[i] + bsums[i >> 11];
    ptr[i] = val;
    if (i < N) cursor[i] = val;
}

__global__ __launch_bounds__(256) void k_fill(const int* __restrict__ ei, int* __restrict__ cursor,
                                              int* __restrict__ csr, int E) {
    int e = blockIdx.x * 256 + threadIdx.x;
    if (e < E) {
        int src = ei[e];
        int pos = atomicAdd(&cursor[ei[E + e]], 1);
        csr[pos] = src;
    }
}

// ---- MFMA GEMM: C[M,256](bf16) = A[M,256] @ Bt^T, Bt = [256 n-rows][256 k]
// epilogue: optional += r2[batch[row]][col]; writes bf16 C, int8 C8 in HEAD-SLICED layout
// h8[head][row][64] (per-row-per-head scale into salsc[row*8 + head*2 + 1]).
__global__ __launch_bounds__(256) void k_gemm(const u16* __restrict__ A, const u16* __restrict__ Bt,
                                              u16* __restrict__ C, u8* __restrict__ C8,
                                              float* __restrict__ salsc, int M,
                                              const float* __restrict__ r2, const int* __restrict__ batch) {
    __shared__ __align__(16) u16 smem[128 * 64 * 2];
    u16* As = smem;
    u16* Bs = smem + 128 * 64;
    const int tid = threadIdx.x;
    const int lane = tid & 63;
    const int wave = tid >> 6;
    const int bm = blockIdx.x >> 1;
    const int bn = blockIdx.x & 1;
    const int m0 = bm * 128, n0 = bn * 128;
    const int wm = wave >> 1, wn = wave & 1;
    const int lm = lane & 15, lq = lane >> 4;
    f32x4 acc[4][4] = {};

    for (int k0 = 0; k0 < 256; k0 += 64) {
        uint4 ra[4], rb[4];
#pragma unroll
        for (int it = 0; it < 4; ++it) {
            int t = tid + 256 * it;
            int m = t >> 3;
            int kc = (t & 7) ^ (m & 7);
            int gm = m0 + m; if (gm > M - 1) gm = M - 1;
            ra[it] = *(const uint4*)(A + (size_t)gm * 256 + k0 + kc * 8);
            rb[it] = *(const uint4*)(Bt + (size_t)(n0 + m) * 256 + k0 + kc * 8);
        }
        __syncthreads();
#pragma unroll
        for (int it = 0; it < 4; ++it) {
            int t = tid + 256 * it;
            *(uint4*)(As + t * 8) = ra[it];
            *(uint4*)(Bs + t * 8) = rb[it];
        }
        __syncthreads();
#pragma unroll
        for (int ks = 0; ks < 2; ++ks) {
            int kq = ks * 4 + lq;
            bf16x8 af[4], bfr[4];
#pragma unroll
            for (int i = 0; i < 4; i++) {
                int m = wm * 64 + i * 16 + lm;
                af[i] = *(const bf16x8*)(As + (m * 8 + (kq ^ (m & 7))) * 8);
                int n = wn * 64 + i * 16 + lm;
                bfr[i] = *(const bf16x8*)(Bs + (n * 8 + (kq ^ (n & 7))) * 8);
            }
#pragma unroll
            for (int i = 0; i < 4; i++)
#pragma unroll
                for (int j = 0; j < 4; j++)
                    acc[i][j] = __builtin_amdgcn_mfma_f32_16x16x32_bf16(af[i], bfr[j], acc[i][j], 0, 0, 0);
        }
    }

    __syncthreads();                       // done with As/Bs; reuse as int8 tile
    u8* lds8 = (u8*)smem;                  // 128 rows x 144-padded
#pragma unroll
    for (int i = 0; i < 4; i++) {
#pragma unroll
        for (int r = 0; r < 4; r++) {
            int rl = wm * 64 + i * 16 + lq * 4 + r;
            int row = m0 + rl;
            bool ok = (row < M);
            const float* r2row = (r2 && ok) ? (r2 + (size_t)batch[row] * 256) : nullptr;
            float v[4];
#pragma unroll
            for (int j = 0; j < 4; j++) {
                v[j] = acc[i][j][r];
                if (r2row) v[j] += r2row[n0 + wn * 64 + j * 16 + lm];
            }
            float mx = fmaxf(fmaxf(fabsf(v[0]), fabsf(v[1])), fmaxf(fabsf(v[2]), fabsf(v[3])));
#pragma unroll
            for (int off = 1; off < 16; off <<= 1) mx = fmaxf(mx, __shfl_xor(mx, off));
            float scl = mx * (1.0f / 127.0f);
            float isc = (mx > 0.f) ? 127.0f / mx : 0.f;
#pragma unroll
            for (int j = 0; j < 4; j++) {
                int col = n0 + wn * 64 + j * 16 + lm;
                if (ok) C[(size_t)row * 256 + col] = f2b(v[j]);
                int q = (int)rintf(v[j] * isc);
                lds8[rl * 144 + wn * 64 + j * 16 + lm] = (u8)(q & 0xff);
            }
            if (ok && lm == 0) salsc[(size_t)row * 8 + (bn * 2 + wn) * 2 + 1] = scl;
        }
    }
    __syncthreads();
    // copy out head-sliced: h8[head][row][64]
    for (int t = tid; t < 1024; t += 256) {      // 128 rows x 2 heads x 4 x 16B
        int rl = t >> 3;
        int seg = t & 7;
        int hh = seg >> 2;                       // head half within this bn
        int off = (seg & 3) * 16;
        int row = m0 + rl;
        if (row < M)
            *(uint4*)(C8 + ((size_t)(bn * 2 + hh) * M + row) * 64 + off) =
                *(const uint4*)(lds8 + rl * 144 + hh * 64 + off);
    }
}

// ---- attention logits -> salsc (als) + ald ----
__global__ __launch_bounds__(256) void k_al(const u16* __restrict__ h, const u16* __restrict__ a_s,
                                            const u16* __restrict__ a_d,
                                            float* __restrict__ salsc, float* __restrict__ ald, int N) {
    int node = blockIdx.x * 4 + (threadIdx.x >> 6);
    if (node >= N) return;
    int lane = threadIdx.x & 63;
    int c0 = lane * 4;
    int head = lane >> 4;
    int ci = c0 & 63;
    ushort4 hv = *(const ushort4*)(h + (size_t)node * 256 + c0);
    float h0 = b2f(hv.x), h1 = b2f(hv.y), h2 = b2f(hv.z), h3 = b2f(hv.w);
    ushort4 sv = *(const ushort4*)(a_s + head * 64 + ci);
    ushort4 dv = *(const ushort4*)(a_d + head * 64 + ci);
    float ps = h0 * b2f(sv.x) + h1 * b2f(sv.y) + h2 * b2f(sv.z) + h3 * b2f(sv.w);
    float pd = h0 * b2f(dv.x) + h1 * b2f(dv.y) + h2 * b2f(dv.z) + h3 * b2f(dv.w);
#pragma unroll
    for (int off = 1; off < 16; off <<= 1) { ps += __shfl_xor(ps, off); pd += __shfl_xor(pd, off); }
    if ((lane & 15) == 0) {
        salsc[(size_t)node * 8 + head * 2] = ps;
        ald[node * 4 + head] = pd;
    }
}

// ---- per-head gather with XCD affinity: block b -> xcd=b&7 -> head=xcd>>1.
// All blocks on one XCD touch a single 3.2MB h8 slice -> L2-resident.
// Weights computed inline (salsc 1.6MB, L2-resident); writes unnormalized
// bf16 partials hacc[node][head][64] + per-node-head sum-of-p ssum.
__global__ __launch_bounds__(256) void k_aggh(
    const u8* __restrict__ h8, const float* __restrict__ salsc, const float* __restrict__ ald_,
    const int* __restrict__ ptr, const int* __restrict__ csr,
    u16* __restrict__ hacc, float* __restrict__ ssum, int N) {
    int b = blockIdx.x;
    int xcd = b & 7;
    int head = xcd >> 1;
    int node = (b >> 3) * 8 + (xcd & 1) * 4 + (threadIdx.x >> 6);
    if (node >= N) return;
    int lane = threadIdx.x & 63;
    float ad = ald_[node * 4 + head];
    const u8* __restrict__ h8h = h8 + (size_t)head * N * 64;
    int beg = ptr[node], end = ptr[node + 1];
    float s = 0.f;
    float aca = 0.f, acb = 0.f, acc2 = 0.f, acd = 0.f;
    int i = beg;
    for (; i + 4 <= end; i += 4) {
        int s0 = csr[i], s1 = csr[i + 1], s2 = csr[i + 2], s3 = csr[i + 3];
        float2 f0 = *(const float2*)(salsc + (size_t)s0 * 8 + head * 2);
        float2 f1 = *(const float2*)(salsc + (size_t)s1 * 8 + head * 2);
        float2 f2v = *(const float2*)(salsc + (size_t)s2 * 8 + head * 2);
        float2 f3 = *(const float2*)(salsc + (size_t)s3 * 8 + head * 2);
        float q0 = (float)(signed char)h8h[(size_t)s0 * 64 + lane];
        float q1 = (float)(signed char)h8h[(size_t)s1 * 64 + lane];
        float q2 = (float)(signed char)h8h[(size_t)s2 * 64 + lane];
        float q3 = (float)(signed char)h8h[(size_t)s3 * 64 + lane];
        float e0 = f0.x + ad; e0 = (e0 > 0.f) ? e0 : 0.2f * e0;
        float e1 = f1.x + ad; e1 = (e1 > 0.f) ? e1 : 0.2f * e1;
        float e2 = f2v.x + ad; e2 = (e2 > 0.f) ? e2 : 0.2f * e2;
        float e3 = f3.x + ad; e3 = (e3 > 0.f) ? e3 : 0.2f * e3;
        float p0 = __expf(e0), p1 = __expf(e1), p2 = __expf(e2), p3 = __expf(e3);
        s += (p0 + p1) + (p2 + p3);
        aca += (p0 * f0.y) * q0;
        acb += (p1 * f1.y) * q1;
        acc2 += (p2 * f2v.y) * q2;
        acd += (p3 * f3.y) * q3;
    }
    for (; i < end; ++i) {
        int s0 = csr[i];
        float2 f0 = *(const float2*)(salsc + (size_t)s0 * 8 + head * 2);
        float q0 = (float)(signed char)h8h[(size_t)s0 * 64 + lane];
        float e0 = f0.x + ad; e0 = (e0 > 0.f) ? e0 : 0.2f * e0;
        float p0 = __expf(e0);
        s += p0;
        aca += (p0 * f0.y) * q0;
    }
    float accv = (aca + acb) + (acc2 + acd);
    hacc[((size_t)node * 4 + head) * 64 + lane] = f2b(accv);
    if (lane == 0) ssum[node * 4 + head] = s;
}

// ---- finalize: self-loop + normalize + bias/BN/LN/ReLU (+pool). Wave per node. ----
__global__ __launch_bounds__(256) void k_aggfin(
    const u16* __restrict__ h, const u16* __restrict__ hacc, const float* __restrict__ ssum,
    const float* __restrict__ salsc, const float* __restrict__ ald_,
    const u16* __restrict__ bias, const u16* __restrict__ bng, const u16* __restrict__ bnb,
    const u16* __restrict__ bnm, const u16* __restrict__ bnv,
    const u16* __restrict__ lng, const u16* __restrict__ lnb,
    u16* __restrict__ xout, float* __restrict__ pool, const int* __restrict__ batch, int N) {
    int node = blockIdx.x * 4 + (threadIdx.x >> 6);
    if (node >= N) return;
    int lane = threadIdx.x & 63;
    float v[4];
#pragma unroll
    for (int hh = 0; hh < 4; ++hh) {
        int c = hh * 64 + lane;
        float als = salsc[(size_t)node * 8 + hh * 2];
        float ad = ald_[node * 4 + hh];
        float es = als + ad; es = (es > 0.f) ? es : 0.2f * es;
        float ps = __expf(es);
        float inv = 1.0f / (ssum[node * 4 + hh] + ps + 1e-16f);
        float selfv = b2f(h[(size_t)node * 256 + c]);
        float acc = b2f(hacc[((size_t)node * 4 + hh) * 64 + lane]);
        float t = (acc + ps * selfv) * inv + b2f(bias[c]);
        v[hh] = (t - b2f(bnm[c])) * (b2f(bng[c]) * rsqrtf(b2f(bnv[c]) + 1e-5f)) + b2f(bnb[c]);
    }
    float sum = v[0] + v[1] + v[2] + v[3];
#pragma unroll
    for (int off = 1; off < 64; off <<= 1) sum += __shfl_xor(sum, off);
    float mu = sum * 0.00390625f;
    float q = 0.f;
#pragma unroll
    for (int hh = 0; hh < 4; ++hh) { v[hh] -= mu; q += v[hh] * v[hh]; }
#pragma unroll
    for (int off = 1; off < 64; off <<= 1) q += __shfl_xor(q, off);
    float rstd = rsqrtf(q * 0.00390625f + 1e-5f);
#pragma unroll
    for (int hh = 0; hh < 4; ++hh) {
        int c = hh * 64 + lane;
        float y = fmaxf(v[hh] * rstd * b2f(lng[c]) + b2f(lnb[c]), 0.f);
        if (xout) xout[(size_t)node * 256 + c] = f2b(y);
        if (pool) atomicAdd(pool + (size_t)batch[node] * 256 + c, y);
    }
}

// ---- r2[b] = x[root_b] @ W2[256:512,:] ----
__global__ __launch_bounds__(256) void k_r2(const u16* __restrict__ xc, const u16* __restrict__ w2,
                                            const int* __restrict__ root, float* __restrict__ r2, int N) {
    __shared__ float xs[256];
    int b = blockIdx.x, c = threadIdx.x;
    int rt = root[b]; if (rt >= N) rt = N - 1; if (rt < 0) rt = 0;
    xs[c] = b2f(xc[(size_t)rt * 256 + c]);
    __syncthreads();
    float acc = 0.f;
    for (int k = 0; k < 256; k++) acc += xs[k] * b2f(w2[(size_t)(256 + k) * 256 + c]);
    r2[b * 256 + c] = acc;
}

// ---- final ----
__global__ void k_final(const float* __restrict__ pool, const u16* __restrict__ x2,
                        const int* __restrict__ root, void* __restrict__ out,
                        const int* __restrict__ flag) {
    int b = blockIdx.x, c = threadIdx.x;
    int r0 = root[b], r1 = root[b + 1];
    int cnt = r1 - r0;
    float inv = 1.0f / (float)(cnt > 1 ? cnt : 1);
    float v0 = pool[b * 256 + c] * inv;
    float v1 = (cnt > 0) ? b2f(x2[(size_t)r0 * 256 + c]) : 0.0f;
    if (*flag) {
        float* o = (float*)out;
        o[b * 512 + c] = v0;
        o[b * 512 + 256 + c] = v1;
    } else {
        u16* o = (u16*)out;
        o[b * 512 + c] = f2b(v0);
        o[b * 512 + 256 + c] = f2b(v1);
    }
}

extern "C" void kernel_launch(void* const* d_in, const int* in_sizes, int n_in,
                              void* d_out, int out_size, void* d_ws, size_t ws_size,
                              hipStream_t stream) {
    u16* outp = (u16*)d_out;
    int ogrid = (out_size + 255) / 256;

    if (n_in != 23) {
        k_sentinel<<<ogrid, 256, 0, stream>>>(outp, out_size, (u16)0x44FA);
        return;
    }

    const void* x_raw = d_in[0];
    const int* ei = (const int*)d_in[1];
    const int* batch = (const int*)d_in[2];
    const int NX = in_sizes[0];
    const int E = in_sizes[1] / 2;
    const int N = in_sizes[2];
    const int NW1 = in_sizes[3];
    const int NW2 = in_sizes[13];
    const int B = NGRAPH;

    char* p = (char*)d_ws;
    auto carve = [&](size_t bytes) -> void* {
        void* r = (void*)p; p += (bytes + 255) & ~(size_t)255; return r;
    };
    u16* xc    = (u16*)carve((size_t)NX * 2);
    u16* w1c   = (u16*)carve((size_t)NW1 * 2);
    u16* w2c   = (u16*)carve((size_t)NW2 * 2);
    u16* sc    = (u16*)carve((size_t)18 * 256 * 2);
    u16* wt1   = (u16*)carve((size_t)65536 * 2);
    u16* wt2   = (u16*)carve((size_t)65536 * 2);
    u16* hbuf  = (u16*)carve((size_t)N * 256 * 2);
    u8*  h8    = (u8*)carve((size_t)N * 256);
    u16* x2    = (u16*)carve((size_t)N * 256 * 2);
    u16* hacc  = (u16*)carve((size_t)N * 256 * 2);
    float* ssum  = (float*)carve((size_t)N * 4 * 4);
    float* salsc = (float*)carve((size_t)N * 8 * 4);
    float* ald = (float*)carve((size_t)N * 4 * 4);
    int* deg    = (int*)carve((size_t)(N + 1) * 4);
    int* pscan  = (int*)carve((size_t)(N + 1) * 4);
    int* ptr    = (int*)carve((size_t)(N + 1) * 4);
    int* cursor = (int*)carve((size_t)N * 4);
    int* csr    = (int*)carve((size_t)E * 4);
    int* bsums  = (int*)carve(1024);
    int* root   = (int*)carve((size_t)(B + 1) * 4);
    float* r2   = (float*)carve((size_t)B * 256 * 4);
    float* pool = (float*)carve((size_t)B * 256 * 4);
    int* flag   = (int*)carve(256);

    size_t needed = (size_t)(p - (char*)d_ws);
    if (needed > ws_size) {
        k_sentinel<<<ogrid, 256, 0, stream>>>(outp, out_size, (u16)0x447A);
        return;
    }

    int zmax = (N + 1) > (B * 256) ? (N + 1) : (B * 256);
    k_init<<<(zmax + 255) / 256, 256, 0, stream>>>((const u16*)x_raw, batch, deg, pool, flag, root, N, B);

    k_cvt4<<<(NX / 4 + 255) / 256, 256, 0, stream>>>(x_raw, xc, NX / 4, flag);
    k_cvt4<<<(NW1 / 4 + 255) / 256, 256, 0, stream>>>(d_in[3], w1c, NW1 / 4, flag);
    k_cvt4<<<(NW2 / 4 + 255) / 256, 256, 0, stream>>>(d_in[13], w2c, NW2 / 4, flag);
    k_cvt_small<<<18, 256, 0, stream>>>(
        d_in[4], d_in[5], d_in[6], d_in[7], d_in[8], d_in[9], d_in[10], d_in[11], d_in[12],
        d_in[14], d_in[15], d_in[16], d_in[17], d_in[18], d_in[19], d_in[20], d_in[21], d_in[22],
        sc, flag);

    k_tr2<<<512, 256, 0, stream>>>(w1c, wt1, w2c, wt2);

    k_hist<<<(E + 255) / 256, 256, 0, stream>>>(ei, deg, E);
    int nb1 = (N + 1 + 2047) / 2048;
    k_scan1<<<nb1, 256, 0, stream>>>(deg, pscan, bsums, N + 1);
    k_scan2<<<1, 64, 0, stream>>>(bsums, nb1);
    k_scan3<<<(N + 1 + 255) / 256, 256, 0, stream>>>(pscan, bsums, ptr, cursor, N + 1, N);
    k_fill<<<(E + 255) / 256, 256, 0, stream>>>(ei, cursor, csr, E);

    int mt = (N + 127) / 128;
    int ngrid = (N + 3) / 4;
    int agrid = ((N + 7) / 8) * 8;
    // layer 1
    k_gemm<<<mt * 2, 256, 0, stream>>>(xc, wt1, hbuf, h8, salsc, N, nullptr, nullptr);
    k_al<<<ngrid, 256, 0, stream>>>(hbuf, sc + 0 * 256, sc + 1 * 256, salsc, ald, N);
    k_aggh<<<agrid, 256, 0, stream>>>(h8, salsc, ald, ptr, csr, hacc, ssum, N);
    k_aggfin<<<ngrid, 256, 0, stream>>>(hbuf, hacc, ssum, salsc, ald,
        sc + 2 * 256, sc + 3 * 256, sc + 4 * 256, sc + 5 * 256, sc + 6 * 256, sc + 7 * 256, sc + 8 * 256,
        x2, nullptr, batch, N);
    // layer 2
    k_r2<<<B, 256, 0, stream>>>(xc, w2c, root, r2, N);
    k_gemm<<<mt * 2, 256, 0, stream>>>(x2, wt2, hbuf, h8, salsc, N, r2, batch);
    k_al<<<ngrid, 256, 0, stream>>>(hbuf, sc + 9 * 256, sc + 10 * 256, salsc, ald, N);
    k_aggh<<<agrid, 256, 0, stream>>>(h8, salsc, ald, ptr, csr, hacc, ssum, N);
    k_aggfin<<<ngrid, 256, 0, stream>>>(hbuf, hacc, ssum, salsc, ald,
        sc + 11 * 256, sc + 12 * 256, sc + 13 * 256, sc + 14 * 256, sc + 15 * 256, sc + 16 * 256, sc + 17 * 256,
        nullptr, pool, batch, N);

    k_final<<<B, 256, 0, stream>>>(pool, x2, root, d_out, flag);
    (void)ws_size;
}

// Round 11
// 706.093 us; speedup vs baseline: 1.1620x; 1.1620x over previous
//
#include <hip/hip_runtime.h>
#include <stdint.h>

typedef unsigned short u16;
typedef unsigned int u32;
typedef unsigned char u8;
typedef __bf16 bf16x8 __attribute__((ext_vector_type(8)));
typedef float f32x4 __attribute__((ext_vector_type(4)));

#define NGRAPH 128

__device__ __forceinline__ float b2f(u16 u) {
    union { u32 i; float f; } c; c.i = ((u32)u) << 16; return c.f;
}
__device__ __forceinline__ u16 f2b(float f) {
    union { float f; u32 i; } c; c.f = f;
    u32 r = c.i + 0x7fffu + ((c.i >> 16) & 1u);
    return (u16)(r >> 16);
}

// ---- sentinel (error paths only) ----
__global__ void k_sentinel(u16* __restrict__ out, int n, u16 pat) {
    int i = blockIdx.x * 256 + threadIdx.x;
    if (i < n) out[i] = pat;
}

// ---- fused init: zero deg/pool, dtype detect (block 0), root search (block 1) ----
__global__ __launch_bounds__(256) void k_init(const u16* __restrict__ x, const int* __restrict__ batch,
                                              int* __restrict__ deg, float* __restrict__ pool,
                                              int* __restrict__ flag, int* __restrict__ root,
                                              int N, int B) {
    __shared__ int cnt;
    int i = blockIdx.x * 256 + threadIdx.x;
    if (i < N + 1) deg[i] = 0;
    if (i < B * 256) pool[i] = 0.0f;
    if (blockIdx.x == 0) {
        if (threadIdx.x == 0) cnt = 0;
        __syncthreads();
        int weird = 0;
        for (int k = threadIdx.x; k < 4096; k += 256) {
            u16 u = x[2 * k];                  // fp32 inputs: random low-mantissa halves
            int e = (u >> 7) & 0xff;
            if (e != 0 && (e < 100 || e > 140)) weird++;
        }
        atomicAdd(&cnt, weird);
        __syncthreads();
        if (threadIdx.x == 0) *flag = (cnt > 1024) ? 1 : 0;   // 1 = fp32 inputs
    } else if (blockIdx.x == 1) {
        int b = threadIdx.x;
        if (b <= B) {
            int lo = 0, hi = N;
            while (lo < hi) { int mid = (lo + hi) >> 1; if (batch[mid] < b) lo = mid + 1; else hi = mid; }
            root[b] = lo;
        }
    }
}

// ---- vectorized convert ----
__global__ __launch_bounds__(256) void k_cvt4(const void* __restrict__ src, u16* __restrict__ dst,
                                              int n4, const int* __restrict__ flag) {
    int i = blockIdx.x * 256 + threadIdx.x;
    if (i >= n4) return;
    if (*flag) {
        float4 v = ((const float4*)src)[i];
        ushort4 o;
        o.x = f2b(v.x); o.y = f2b(v.y); o.z = f2b(v.z); o.w = f2b(v.w);
        ((ushort4*)dst)[i] = o;
    } else {
        ((ushort4*)dst)[i] = ((const ushort4*)src)[i];
    }
}

// ---- small-vector convert: 18 blocks x 256 ----
__global__ __launch_bounds__(256) void k_cvt_small(
    const void* p0, const void* p1, const void* p2, const void* p3, const void* p4,
    const void* p5, const void* p6, const void* p7, const void* p8, const void* p9,
    const void* p10, const void* p11, const void* p12, const void* p13, const void* p14,
    const void* p15, const void* p16, const void* p17,
    u16* __restrict__ dst, const int* __restrict__ flag) {
    const void* ps[18] = {p0,p1,p2,p3,p4,p5,p6,p7,p8,p9,p10,p11,p12,p13,p14,p15,p16,p17};
    int f = *flag;
    int vec = blockIdx.x;
    int j = threadIdx.x;
    const void* s = ps[vec];
    dst[vec * 256 + j] = f ? f2b(((const float*)s)[j]) : ((const u16*)s)[j];
}

// ---- dual transpose 256x256 ----
__global__ __launch_bounds__(256) void k_tr2(const u16* __restrict__ w1, u16* __restrict__ wt1,
                                             const u16* __restrict__ w2, u16* __restrict__ wt2) {
    int idx = blockIdx.x * 256 + threadIdx.x;
    int halfsel = idx >> 16;
    int j = idx & 65535;
    int n = j >> 8, k = j & 255;
    if (halfsel == 0) wt1[n * 256 + k] = w1[k * 256 + n];
    else              wt2[n * 256 + k] = w2[k * 256 + n];
}

__global__ __launch_bounds__(256) void k_hist(const int* __restrict__ ei, int* __restrict__ deg, int E) {
    int e = blockIdx.x * 256 + threadIdx.x;
    if (e < E) atomicAdd(&deg[ei[E + e]], 1);
}

__global__ __launch_bounds__(256) void k_scan1(const int* __restrict__ in, int* __restrict__ out,
                                               int* __restrict__ bsums, int total) {
    __shared__ int lds[256];
    int tid = threadIdx.x;
    int base = blockIdx.x * 2048 + tid * 8;
    int v[8]; int ts = 0;
#pragma unroll
    for (int r = 0; r < 8; r++) { int i = base + r; int x = (i < total) ? in[i] : 0; v[r] = x; ts += x; }
    lds[tid] = ts;
    __syncthreads();
    for (int off = 1; off < 256; off <<= 1) {
        int t = (tid >= off) ? lds[tid - off] : 0;
        __syncthreads();
        lds[tid] += t;
        __syncthreads();
    }
    int run = lds[tid] - ts;
#pragma unroll
    for (int r = 0; r < 8; r++) { int i = base + r; if (i < total) out[i] = run; run += v[r]; }
    if (tid == 255) bsums[blockIdx.x] = lds[255];
}

__global__ void k_scan2(int* __restrict__ bsums, int nb) {
    if (threadIdx.x == 0 && blockIdx.x == 0) {
        int run = 0;
        for (int i = 0; i < nb; i++) { int t = bsums[i]; bsums[i] = run; run += t; }
    }
}

__global__ __launch_bounds__(256) void k_scan3(const int* __restrict__ pscan, const int* __restrict__ bsums,
                                               int* __restrict__ ptr, int* __restrict__ cursor,
                                               int total, int N) {
    int i = blockIdx.x * 256 + threadIdx.x;
    if (i >= total) return;
    int val = pscan[i] + bsums[i >> 11];
    ptr[i] = val;
    if (i < N) cursor[i] = val;
}

__global__ __launch_bounds__(256) void k_fill(const int* __restrict__ ei, int* __restrict__ cursor,
                                              int* __restrict__ csr, int E) {
    int e = blockIdx.x * 256 + threadIdx.x;
    if (e < E) {
        int src = ei[e];
        int pos = atomicAdd(&cursor[ei[E + e]], 1);
        csr[pos] = src;
    }
}

// ---- MFMA GEMM: C[M,256](bf16) = A[M,256] @ Bt^T, Bt = [256 n-rows][256 k]
// epilogue: optional += r2[batch[row]][col]; writes bf16 C; int8 C8 head-sliced h8[head][row][64]
// with per-row-per-head scale -> salsc[row*8+head*2+1]; FUSED attention logits:
// als -> salsc[row*8+head*2], ald -> ald[row*4+head] (each wave's 64 cols = one head).
__global__ __launch_bounds__(256) void k_gemm(const u16* __restrict__ A, const u16* __restrict__ Bt,
                                              u16* __restrict__ C, u8* __restrict__ C8,
                                              float* __restrict__ salsc, float* __restrict__ ald,
                                              const u16* __restrict__ a_s, const u16* __restrict__ a_d,
                                              int M,
                                              const float* __restrict__ r2, const int* __restrict__ batch) {
    __shared__ __align__(16) u16 smem[128 * 64 * 2];
    u16* As = smem;
    u16* Bs = smem + 128 * 64;
    const int tid = threadIdx.x;
    const int lane = tid & 63;
    const int wave = tid >> 6;
    const int bm = blockIdx.x >> 1;
    const int bn = blockIdx.x & 1;
    const int m0 = bm * 128, n0 = bn * 128;
    const int wm = wave >> 1, wn = wave & 1;
    const int lm = lane & 15, lq = lane >> 4;
    const int head = bn * 2 + wn;
    f32x4 acc[4][4] = {};

    for (int k0 = 0; k0 < 256; k0 += 64) {
        uint4 ra[4], rb[4];
#pragma unroll
        for (int it = 0; it < 4; ++it) {
            int t = tid + 256 * it;
            int m = t >> 3;
            int kc = (t & 7) ^ (m & 7);
            int gm = m0 + m; if (gm > M - 1) gm = M - 1;
            ra[it] = *(const uint4*)(A + (size_t)gm * 256 + k0 + kc * 8);
            rb[it] = *(const uint4*)(Bt + (size_t)(n0 + m) * 256 + k0 + kc * 8);
        }
        __syncthreads();
#pragma unroll
        for (int it = 0; it < 4; ++it) {
            int t = tid + 256 * it;
            *(uint4*)(As + t * 8) = ra[it];
            *(uint4*)(Bs + t * 8) = rb[it];
        }
        __syncthreads();
#pragma unroll
        for (int ks = 0; ks < 2; ++ks) {
            int kq = ks * 4 + lq;
            bf16x8 af[4], bfr[4];
#pragma unroll
            for (int i = 0; i < 4; i++) {
                int m = wm * 64 + i * 16 + lm;
                af[i] = *(const bf16x8*)(As + (m * 8 + (kq ^ (m & 7))) * 8);
                int n = wn * 64 + i * 16 + lm;
                bfr[i] = *(const bf16x8*)(Bs + (n * 8 + (kq ^ (n & 7))) * 8);
            }
#pragma unroll
            for (int i = 0; i < 4; i++)
#pragma unroll
                for (int j = 0; j < 4; j++)
                    acc[i][j] = __builtin_amdgcn_mfma_f32_16x16x32_bf16(af[i], bfr[j], acc[i][j], 0, 0, 0);
        }
    }

    // attention vectors for this wave's head (constant over rows)
    float asv[4], adv[4];
#pragma unroll
    for (int j = 0; j < 4; j++) {
        asv[j] = b2f(a_s[head * 64 + j * 16 + lm]);
        adv[j] = b2f(a_d[head * 64 + j * 16 + lm]);
    }

    __syncthreads();                       // done with As/Bs; reuse as int8 tile
    u8* lds8 = (u8*)smem;                  // 128 rows x 144-padded
#pragma unroll
    for (int i = 0; i < 4; i++) {
#pragma unroll
        for (int r = 0; r < 4; r++) {
            int rl = wm * 64 + i * 16 + lq * 4 + r;
            int row = m0 + rl;
            bool ok = (row < M);
            const float* r2row = (r2 && ok) ? (r2 + (size_t)batch[row] * 256) : nullptr;
            float v[4];
#pragma unroll
            for (int j = 0; j < 4; j++) {
                v[j] = acc[i][j][r];
                if (r2row) v[j] += r2row[n0 + wn * 64 + j * 16 + lm];
            }
            // fused attention logits (16-lane reduction within quad)
            float ps = v[0] * asv[0] + v[1] * asv[1] + v[2] * asv[2] + v[3] * asv[3];
            float pd = v[0] * adv[0] + v[1] * adv[1] + v[2] * adv[2] + v[3] * adv[3];
#pragma unroll
            for (int off = 1; off < 16; off <<= 1) { ps += __shfl_xor(ps, off); pd += __shfl_xor(pd, off); }
            float mx = fmaxf(fmaxf(fabsf(v[0]), fabsf(v[1])), fmaxf(fabsf(v[2]), fabsf(v[3])));
#pragma unroll
            for (int off = 1; off < 16; off <<= 1) mx = fmaxf(mx, __shfl_xor(mx, off));
            float scl = mx * (1.0f / 127.0f);
            float isc = (mx > 0.f) ? 127.0f / mx : 0.f;
#pragma unroll
            for (int j = 0; j < 4; j++) {
                int col = n0 + wn * 64 + j * 16 + lm;
                if (ok) C[(size_t)row * 256 + col] = f2b(v[j]);
                int q = (int)rintf(v[j] * isc);
                lds8[rl * 144 + wn * 64 + j * 16 + lm] = (u8)(q & 0xff);
            }
            if (ok && lm == 0) {
                salsc[(size_t)row * 8 + head * 2] = ps;
                salsc[(size_t)row * 8 + head * 2 + 1] = scl;
                ald[(size_t)row * 4 + head] = pd;
            }
        }
    }
    __syncthreads();
    // copy out head-sliced: h8[head][row][64]
    for (int t = tid; t < 1024; t += 256) {      // 128 rows x 2 heads x 4 x 16B
        int rl = t >> 3;
        int seg = t & 7;
        int hh = seg >> 2;
        int off = (seg & 3) * 16;
        int row = m0 + rl;
        if (row < M)
            *(uint4*)(C8 + ((size_t)(bn * 2 + hh) * M + row) * 64 + off) =
                *(const uint4*)(lds8 + rl * 144 + hh * 64 + off);
    }
}

// ---- edge weights: aw[h][e] = exp(leaky(als[src]+ald[dst])) * scale8[src,h];
// invs[node][h] = 1/(sum_p + p_self); selfw[node][h] = p_self * invs.
// wave per node: lane = el*4 + h (16 edges x 4 heads per chunk).
__global__ __launch_bounds__(256) void k_attw(
    const float* __restrict__ salsc, const float* __restrict__ ald_,
    const int* __restrict__ ptr, const int* __restrict__ csr,
    float* __restrict__ aw, float* __restrict__ invs, float* __restrict__ selfw, int N, int E) {
    int node = blockIdx.x * 4 + (threadIdx.x >> 6);
    if (node >= N) return;
    int lane = threadIdx.x & 63;
    int h = lane & 3;
    int el = lane >> 2;
    int beg = ptr[node], end = ptr[node + 1];
    float ad = ald_[node * 4 + h];
    float s = 0.f;
    for (int i0 = beg; i0 < end; i0 += 16) {
        int e = i0 + el;
        if (e < end) {
            int src = csr[e];
            float2 f = *(const float2*)(salsc + (size_t)src * 8 + h * 2);
            float lg = f.x + ad; lg = (lg > 0.f) ? lg : 0.2f * lg;
            float p = __expf(lg);
            aw[(size_t)h * E + e] = p * f.y;
            s += p;
        }
    }
#pragma unroll
    for (int off = 4; off < 64; off <<= 1) s += __shfl_xor(s, off);
    float es = salsc[(size_t)node * 8 + h * 2] + ad; es = (es > 0.f) ? es : 0.2f * es;
    float pself = __expf(es);
    s += pself;
    if (el == 0) {
        float inv = 1.0f / (s + 1e-16f);
        invs[node * 4 + h] = inv;
        selfw[node * 4 + h] = pself * inv;
    }
}

// ---- head-phased aggregation with XCD-rotated phase order: phase ph handles head
// (ph + blockIdx&3)&3, so concurrent blocks on one XCD mostly hit one 3.2MB slice.
// acc[] statically indexed (head only used in addresses). Fused finalize.
__global__ __launch_bounds__(256) void k_agg6(
    const u16* __restrict__ h, const u8* __restrict__ h8,
    const float* __restrict__ aw, const float* __restrict__ invs_, const float* __restrict__ selfw_,
    const int* __restrict__ ptr, const int* __restrict__ csr,
    const u16* __restrict__ bias, const u16* __restrict__ bng, const u16* __restrict__ bnb,
    const u16* __restrict__ bnm, const u16* __restrict__ bnv,
    const u16* __restrict__ lng, const u16* __restrict__ lnb,
    u16* __restrict__ xout, float* __restrict__ pool, const int* __restrict__ batch, int N, int E) {
    int node = blockIdx.x * 4 + (threadIdx.x >> 6);
    if (node >= N) return;
    int lane = threadIdx.x & 63;
    int rot = blockIdx.x & 3;
    int beg = ptr[node], end = ptr[node + 1];
    float acc[4];
    int hd[4];
#pragma unroll
    for (int ph = 0; ph < 4; ++ph) {
        int hh = (ph + rot) & 3;
        hd[ph] = hh;
        const float* awh = aw + (size_t)hh * E;
        const u8* h8h = h8 + (size_t)hh * N * 64;
        float sa = 0.f, sb = 0.f, sc2 = 0.f, sd = 0.f;
        int i = beg;
        for (; i + 4 <= end; i += 4) {
            int s0 = csr[i], s1 = csr[i + 1], s2 = csr[i + 2], s3 = csr[i + 3];
            float w0 = awh[i], w1 = awh[i + 1], w2 = awh[i + 2], w3 = awh[i + 3];
            float q0 = (float)(signed char)h8h[(size_t)s0 * 64 + lane];
            float q1 = (float)(signed char)h8h[(size_t)s1 * 64 + lane];
            float q2 = (float)(signed char)h8h[(size_t)s2 * 64 + lane];
            float q3 = (float)(signed char)h8h[(size_t)s3 * 64 + lane];
            sa += w0 * q0; sb += w1 * q1; sc2 += w2 * q2; sd += w3 * q3;
        }
        for (; i < end; ++i) {
            int s0 = csr[i];
            float w0 = awh[i];
            sa += w0 * (float)(signed char)h8h[(size_t)s0 * 64 + lane];
        }
        acc[ph] = (sa + sb) + (sc2 + sd);
    }
    float v[4];
#pragma unroll
    for (int ph = 0; ph < 4; ++ph) {
        int hh = hd[ph];
        int c = hh * 64 + lane;
        float inv = invs_[node * 4 + hh];
        float sw = selfw_[node * 4 + hh];
        float self = b2f(h[(size_t)node * 256 + c]);
        float t = acc[ph] * inv + sw * self + b2f(bias[c]);
        v[ph] = (t - b2f(bnm[c])) * (b2f(bng[c]) * rsqrtf(b2f(bnv[c]) + 1e-5f)) + b2f(bnb[c]);
    }
    float sum = v[0] + v[1] + v[2] + v[3];
#pragma unroll
    for (int off = 1; off < 64; off <<= 1) sum += __shfl_xor(sum, off);
    float mu = sum * 0.00390625f;
    float q = 0.f;
#pragma unroll
    for (int ph = 0; ph < 4; ++ph) { v[ph] -= mu; q += v[ph] * v[ph]; }
#pragma unroll
    for (int off = 1; off < 64; off <<= 1) q += __shfl_xor(q, off);
    float rstd = rsqrtf(q * 0.00390625f + 1e-5f);
#pragma unroll
    for (int ph = 0; ph < 4; ++ph) {
        int hh = hd[ph];
        int c = hh * 64 + lane;
        float y = fmaxf(v[ph] * rstd * b2f(lng[c]) + b2f(lnb[c]), 0.f);
        if (xout) xout[(size_t)node * 256 + c] = f2b(y);
        if (pool) atomicAdd(pool + (size_t)batch[node] * 256 + c, y);
    }
}

// ---- r2[b] = x[root_b] @ W2[256:512,:] ----
__global__ __launch_bounds__(256) void k_r2(const u16* __restrict__ xc, const u16* __restrict__ w2,
                                            const int* __restrict__ root, float* __restrict__ r2, int N) {
    __shared__ float xs[256];
    int b = blockIdx.x, c = threadIdx.x;
    int rt = root[b]; if (rt >= N) rt = N - 1; if (rt < 0) rt = 0;
    xs[c] = b2f(xc[(size_t)rt * 256 + c]);
    __syncthreads();
    float acc = 0.f;
    for (int k = 0; k < 256; k++) acc += xs[k] * b2f(w2[(size_t)(256 + k) * 256 + c]);
    r2[b * 256 + c] = acc;
}

// ---- final ----
__global__ void k_final(const float* __restrict__ pool, const u16* __restrict__ x2,
                        const int* __restrict__ root, void* __restrict__ out,
                        const int* __restrict__ flag) {
    int b = blockIdx.x, c = threadIdx.x;
    int r0 = root[b], r1 = root[b + 1];
    int cnt = r1 - r0;
    float inv = 1.0f / (float)(cnt > 1 ? cnt : 1);
    float v0 = pool[b * 256 + c] * inv;
    float v1 = (cnt > 0) ? b2f(x2[(size_t)r0 * 256 + c]) : 0.0f;
    if (*flag) {
        float* o = (float*)out;
        o[b * 512 + c] = v0;
        o[b * 512 + 256 + c] = v1;
    } else {
        u16* o = (u16*)out;
        o[b * 512 + c] = f2b(v0);
        o[b * 512 + 256 + c] = f2b(v1);
    }
}

extern "C" void kernel_launch(void* const* d_in, const int* in_sizes, int n_in,
                              void* d_out, int out_size, void* d_ws, size_t ws_size,
                              hipStream_t stream) {
    u16* outp = (u16*)d_out;
    int ogrid = (out_size + 255) / 256;

    if (n_in != 23) {
        k_sentinel<<<ogrid, 256, 0, stream>>>(outp, out_size, (u16)0x44FA);
        return;
    }

    const void* x_raw = d_in[0];
    const int* ei = (const int*)d_in[1];
    const int* batch = (const int*)d_in[2];
    const int NX = in_sizes[0];
    const int E = in_sizes[1] / 2;
    const int N = in_sizes[2];
    const int NW1 = in_sizes[3];
    const int NW2 = in_sizes[13];
    const int B = NGRAPH;

    char* p = (char*)d_ws;
    auto carve = [&](size_t bytes) -> void* {
        void* r = (void*)p; p += (bytes + 255) & ~(size_t)255; return r;
    };
    u16* xc    = (u16*)carve((size_t)NX * 2);
    u16* w1c   = (u16*)carve((size_t)NW1 * 2);
    u16* w2c   = (u16*)carve((size_t)NW2 * 2);
    u16* sc    = (u16*)carve((size_t)18 * 256 * 2);
    u16* wt1   = (u16*)carve((size_t)65536 * 2);
    u16* wt2   = (u16*)carve((size_t)65536 * 2);
    u16* hbuf  = (u16*)carve((size_t)N * 256 * 2);
    u8*  h8    = (u8*)carve((size_t)N * 256);
    u16* x2    = (u16*)carve((size_t)N * 256 * 2);
    float* salsc = (float*)carve((size_t)N * 8 * 4);
    float* ald = (float*)carve((size_t)N * 4 * 4);
    float* aw  = (float*)carve((size_t)E * 4 * 4);
    float* invs  = (float*)carve((size_t)N * 4 * 4);
    float* selfw = (float*)carve((size_t)N * 4 * 4);
    int* deg    = (int*)carve((size_t)(N + 1) * 4);
    int* pscan  = (int*)carve((size_t)(N + 1) * 4);
    int* ptr    = (int*)carve((size_t)(N + 1) * 4);
    int* cursor = (int*)carve((size_t)N * 4);
    int* csr    = (int*)carve((size_t)E * 4);
    int* bsums  = (int*)carve(1024);
    int* root   = (int*)carve((size_t)(B + 1) * 4);
    float* r2   = (float*)carve((size_t)B * 256 * 4);
    float* pool = (float*)carve((size_t)B * 256 * 4);
    int* flag   = (int*)carve(256);

    size_t needed = (size_t)(p - (char*)d_ws);
    if (needed > ws_size) {
        k_sentinel<<<ogrid, 256, 0, stream>>>(outp, out_size, (u16)0x447A);
        return;
    }

    int zmax = (N + 1) > (B * 256) ? (N + 1) : (B * 256);
    k_init<<<(zmax + 255) / 256, 256, 0, stream>>>((const u16*)x_raw, batch, deg, pool, flag, root, N, B);

    k_cvt4<<<(NX / 4 + 255) / 256, 256, 0, stream>>>(x_raw, xc, NX / 4, flag);
    k_cvt4<<<(NW1 / 4 + 255) / 256, 256, 0, stream>>>(d_in[3], w1c, NW1 / 4, flag);
    k_cvt4<<<(NW2 / 4 + 255) / 256, 256, 0, stream>>>(d_in[13], w2c, NW2 / 4, flag);
    k_cvt_small<<<18, 256, 0, stream>>>(
        d_in[4], d_in[5], d_in[6], d_in[7], d_in[8], d_in[9], d_in[10], d_in[11], d_in[12],
        d_in[14], d_in[15], d_in[16], d_in[17], d_in[18], d_in[19], d_in[20], d_in[21], d_in[22],
        sc, flag);

    k_tr2<<<512, 256, 0, stream>>>(w1c, wt1, w2c, wt2);

    k_hist<<<(E + 255) / 256, 256, 0, stream>>>(ei, deg, E);
    int nb1 = (N + 1 + 2047) / 2048;
    k_scan1<<<nb1, 256, 0, stream>>>(deg, pscan, bsums, N + 1);
    k_scan2<<<1, 64, 0, stream>>>(bsums, nb1);
    k_scan3<<<(N + 1 + 255) / 256, 256, 0, stream>>>(pscan, bsums, ptr, cursor, N + 1, N);
    k_fill<<<(E + 255) / 256, 256, 0, stream>>>(ei, cursor, csr, E);

    int mt = (N + 127) / 128;
    int ngrid = (N + 3) / 4;
    // layer 1
    k_gemm<<<mt * 2, 256, 0, stream>>>(xc, wt1, hbuf, h8, salsc, ald,
                                       sc + 0 * 256, sc + 1 * 256, N, nullptr, nullptr);
    k_attw<<<ngrid, 256, 0, stream>>>(salsc, ald, ptr, csr, aw, invs, selfw, N, E);
    k_agg6<<<ngrid, 256, 0, stream>>>(hbuf, h8, aw, invs, selfw, ptr, csr,
        sc + 2 * 256, sc + 3 * 256, sc + 4 * 256, sc + 5 * 256, sc + 6 * 256, sc + 7 * 256, sc + 8 * 256,
        x2, nullptr, batch, N, E);
    // layer 2
    k_r2<<<B, 256, 0, stream>>>(xc, w2c, root, r2, N);
    k_gemm<<<mt * 2, 256, 0, stream>>>(x2, wt2, hbuf, h8, salsc, ald,
                                       sc + 9 * 256, sc + 10 * 256, N, r2, batch);
    k_attw<<<ngrid, 256, 0, stream>>>(salsc, ald, ptr, csr, aw, invs, selfw, N, E);
    k_agg6<<<ngrid, 256, 0, stream>>>(hbuf, h8, aw, invs, selfw, ptr, csr,
        sc + 11 * 256, sc + 12 * 256, sc + 13 * 256, sc + 14 * 256, sc + 15 * 256, sc + 16 * 256, sc + 17 * 256,
        nullptr, pool, batch, N, E);

    k_final<<<B, 256, 0, stream>>>(pool, x2, root, d_out, flag);
    (void)ws_size;
}